// Round 10
// baseline (152.664 us; speedup 1.0000x reference)
//
#include <hip/hip_runtime.h>

#define B_  8
#define C_  128
#define H_  128
#define W_  256
#define HW_ (H_ * W_)
#define TH  8
#define TW  32
#define F2R   10                  // f2 tile rows per di-group (TH + 2)
#define F2RS  48                  // f2 row stride (dw): +16 banks/row -> <=2-way
#define F2PT  (F2R * F2RS)        // 480 dw per f2 pair-tile
#define F1RS  40                  // f1 row stride (dw): +8 banks/row -> <=2-way
#define F1PT  (TH * F1RS)         // 320 dw per f1 pair-tile
#define F1OFF (2 * F2PT)          // 960
#define BUFN  (F1OFF + 2 * F1PT)  // 1600 dw per buffer (6.4 KB; dbuf 12.8 KB)
#define NTHREADS 192

typedef __fp16 h2 __attribute__((ext_vector_type(2)));

__device__ __forceinline__ float dot2f16(unsigned int a, unsigned int b, float c) {
#if __has_builtin(__builtin_amdgcn_fdot2)
    return __builtin_amdgcn_fdot2(__builtin_bit_cast(h2, a),
                                  __builtin_bit_cast(h2, b), c, false);
#else
    h2 ha = __builtin_bit_cast(h2, a), hb = __builtin_bit_cast(h2, b);
    return c + (float)ha.x * (float)hb.x + (float)ha.y * (float)hb.y;
#endif
}

__device__ __forceinline__ unsigned int pk(float x, float y) {
    h2 r = __builtin_amdgcn_cvt_pkrtz(x, y);
    return __builtin_bit_cast(unsigned int, r);
}

// 3-wave block (192 thr), wave = di within group g = blockIdx.z%3.
// Per-wave work identical to r9 (3 f2 + 1 f1 b128 per pair, acc[9][4]);
// small blocks -> ~10 co-resident blocks/CU for latency hiding.
// Stage = 2 pairs (4 ch), 32 stages, depth-1.5 pipeline, raw s_barrier +
// lgkmcnt(0) only (counted vmcnt on staged loads). bounds(192,3) = the
// r3/r6/r9-proven generous-cap allocation regime.
__global__ __launch_bounds__(NTHREADS, 3) void cv_kernel(
    const float* __restrict__ f1g, const float* __restrict__ f2g,
    float* __restrict__ outg) {
    __shared__ __align__(16) unsigned int lds[2][BUFN];

    const int tid = threadIdx.x;
    const int w0 = blockIdx.x * TW;
    const int h0 = blockIdx.y * TH;
    const int g  = blockIdx.z % 3;     // di group
    const int b  = blockIdx.z / 3;
    const int dib = 3 * g;             // di base for this block

    // ---- slot A (all 192): f2 units 0..191 of 2 pairs x 10 rows x 10 units ----
    int offA, ldA;
    float mA;
    {
        int p  = (tid >= 100);
        int ul = tid - p * 100;        // p0: 0..99, p1: 0..91
        int r  = ul / 10, u = ul - 10 * r;
        int gh = h0 - 4 + dib + r, gw = w0 - 4 + 4 * u;
        bool valid = (gh >= 0) && (gh < H_) && (gw >= 0) && (gw <= W_ - 4);
        int ghc = min(max(gh, 0), H_ - 1);
        int gwc = min(max(gw, 0), W_ - 4);
        offA = ((b * C_ + 2 * p) * H_ + ghc) * W_ + gwc;
        ldA  = p * F2PT + r * F2RS + 4 * u;
        mA   = valid ? 1.f : 0.f;
    }
    // ---- slot C: tid<8 -> f2 pair1 row9 units 2..9; tid 8..135 -> f1 ----
    const bool roleC = (tid < 136);
    int offC = 0, ldC = 0;
    float mC = 0.f;
    const float* pC = f1g;
    if (tid < 8) {
        int r = 9, u = 2 + tid;
        int gh = h0 - 4 + dib + r, gw = w0 - 4 + 4 * u;
        bool valid = (gh >= 0) && (gh < H_) && (gw >= 0) && (gw <= W_ - 4);
        int ghc = min(max(gh, 0), H_ - 1);
        int gwc = min(max(gw, 0), W_ - 4);
        offC = ((b * C_ + 2) * H_ + ghc) * W_ + gwc;   // pair 1
        pC   = f2g;
        ldC  = F2PT + r * F2RS + 4 * u;
        mC   = valid ? 1.f : 0.f;
    } else if (roleC) {
        int t = tid - 8;               // 0..127: f1 2 pairs x 8 rows x 8 units
        int p = t >> 6, r = (t >> 3) & 7, u = t & 7;
        offC = ((b * C_ + 2 * p) * H_ + h0 + r) * W_ + w0 + 4 * u;
        pC   = f1g;
        ldC  = F1OFF + p * F1PT + r * F1RS + 4 * u;
        mC   = 1.f;
    }

#define LOADST()                                                              \
    do {                                                                      \
        aA = *(const float4*)(f2g + offA);                                    \
        bA = *(const float4*)(f2g + offA + HW_);                              \
        offA += 4 * HW_;                                                      \
        if (roleC) {                                                          \
            cC = *(const float4*)(pC + offC);                                 \
            dC = *(const float4*)(pC + offC + HW_);                           \
            offC += 4 * HW_;                                                  \
        }                                                                     \
    } while (0)

#define STOREST(bi)                                                           \
    do {                                                                      \
        uint4 wv_;                                                            \
        wv_.x = pk(aA.x * mA, bA.x * mA);                                     \
        wv_.y = pk(aA.y * mA, bA.y * mA);                                     \
        wv_.z = pk(aA.z * mA, bA.z * mA);                                     \
        wv_.w = pk(aA.w * mA, bA.w * mA);                                     \
        *(uint4*)(&lds[bi][ldA]) = wv_;                                       \
        if (roleC) {                                                          \
            uint4 w2_;                                                        \
            w2_.x = pk(cC.x * mC, dC.x * mC);                                 \
            w2_.y = pk(cC.y * mC, dC.y * mC);                                 \
            w2_.z = pk(cC.z * mC, dC.z * mC);                                 \
            w2_.w = pk(cC.w * mC, dC.w * mC);                                 \
            *(uint4*)(&lds[bi][ldC]) = w2_;                                   \
        }                                                                     \
    } while (0)

#define BAR()                                                                 \
    do {                                                                      \
        asm volatile("s_waitcnt lgkmcnt(0)" ::: "memory");                    \
        __builtin_amdgcn_s_barrier();                                         \
    } while (0)

    // ---- compute mapping ----
    const int wv   = tid >> 6;        // 0..2 -> di offset within group
    const int lane = tid & 63;
    const int hh   = lane >> 3;       // 0..7
    const int sc   = lane & 7;        // 0..7, 4-px strip
    const int rd0  = (hh + wv) * F2RS + 4 * sc;   // f2 units sc..sc+2
    const int rf0  = F1OFF + hh * F1RS + 4 * sc;  // f1 unit sc (pair 0 base)

    float acc[9][4];
#pragma unroll
    for (int j = 0; j < 9; ++j)
#pragma unroll
        for (int p = 0; p < 4; ++p) acc[j][p] = 0.f;

#define COMPUTE(bi)                                                           \
    do {                                                                      \
        _Pragma("unroll")                                                     \
        for (int q = 0; q < 2; ++q) {                                         \
            const unsigned int* bf2 = &lds[bi][q * F2PT];                     \
            const unsigned int* bf1 = &lds[bi][q * F1PT];                     \
            uint4 fa = *(const uint4*)(bf2 + rd0);                            \
            uint4 fb = *(const uint4*)(bf2 + rd0 + 4);                        \
            uint4 fc = *(const uint4*)(bf2 + rd0 + 8);                        \
            uint4 ga = *(const uint4*)(bf1 + rf0);                            \
            unsigned int f2u[12] = {fa.x, fa.y, fa.z, fa.w, fb.x, fb.y,       \
                                    fb.z, fb.w, fc.x, fc.y, fc.z, fc.w};      \
            unsigned int f1u[4]  = {ga.x, ga.y, ga.z, ga.w};                  \
            _Pragma("unroll")                                                 \
            for (int j = 0; j < 9; ++j)                                       \
                _Pragma("unroll")                                             \
                for (int p = 0; p < 4; ++p)                                   \
                    acc[j][p] = dot2f16(f1u[p], f2u[p + j], acc[j][p]);       \
        }                                                                     \
    } while (0)

    float4 aA, bA, cC, dC;

    // prologue: stage 0 -> buf0
    LOADST();
    STOREST(0);
    BAR();

    // 32 stages of 4 channels
    for (int st = 0; st < 30; st += 2) {
        LOADST();                    // stage st+1 (in flight over compute)
        COMPUTE(0);                  // stage st
        STOREST(1);                  // stage st+1 (counted vmcnt)
        BAR();
        LOADST();                    // stage st+2
        COMPUTE(1);                  // stage st+1
        STOREST(0);                  // stage st+2
        BAR();
    }
    LOADST();                        // stage 31
    COMPUTE(0);                      // stage 30
    STOREST(1);                      // stage 31
    BAR();
    COMPUTE(1);                      // stage 31

    // ---- epilogue: mean over C and store ----
    const float inv = 1.0f / 128.0f;
    const int di = dib + wv;
    int obase = ((b * 81 + di * 9) * H_ + h0 + hh) * W_ + w0 + 4 * sc;
#pragma unroll
    for (int j = 0; j < 9; ++j) {
        float4 o = make_float4(acc[j][0] * inv, acc[j][1] * inv,
                               acc[j][2] * inv, acc[j][3] * inv);
        *(float4*)(outg + obase) = o;
        obase += HW_;
    }
}

extern "C" void kernel_launch(void* const* d_in, const int* in_sizes, int n_in,
                              void* d_out, int out_size, void* d_ws, size_t ws_size,
                              hipStream_t stream) {
    const float* f1 = (const float*)d_in[0];
    const float* f2 = (const float*)d_in[1];
    float* out = (float*)d_out;
    dim3 grid(W_ / TW, H_ / TH, B_ * 3);   // 8 x 16 x 24 = 3072 blocks
    cv_kernel<<<grid, NTHREADS, 0, stream>>>(f1, f2, out);
}

// Round 11
// 130.747 us; speedup vs baseline: 1.1676x; 1.1676x over previous
//
#include <hip/hip_runtime.h>

#define B_  8
#define C_  128
#define H_  128
#define W_  256
#define HW_ (H_ * W_)
#define TH  8
#define TW  32
#define NPAIR 4                    // channel-pairs per stage (8 channels/stage)
#define F2RS 72                    // f2 row stride (dw): banks (8r+4u)%32, 2-way free
#define F2PT (16 * F2RS)           // 1152 dw per f2 pair-tile (16 rows)
#define F1RS 40                    // f1 row stride (dw): banks (8r+4u)%32, 2-way free
#define F1PT (8 * F1RS)            // 320 dw per f1 pair-tile (8 rows)
#define F1OFF (NPAIR * F2PT)       // 4608
#define BUFN (F1OFF + NPAIR * F1PT) // 5888 dw per buffer (23.0 KB; dbuf 46 KB)
#define NTHREADS 576

typedef __fp16 h2 __attribute__((ext_vector_type(2)));

__device__ __forceinline__ float dot2f16(unsigned int a, unsigned int b, float c) {
#if __has_builtin(__builtin_amdgcn_fdot2)
    return __builtin_amdgcn_fdot2(__builtin_bit_cast(h2, a),
                                  __builtin_bit_cast(h2, b), c, false);
#else
    h2 ha = __builtin_bit_cast(h2, a), hb = __builtin_bit_cast(h2, b);
    return c + (float)ha.x * (float)hb.x + (float)ha.y * (float)hb.y;
#endif
}

__device__ __forceinline__ unsigned int pk(float x, float y) {
    h2 r = __builtin_amdgcn_cvt_pkrtz(x, y);
    return __builtin_bit_cast(unsigned int, r);
}

// 9-wave block, wave = di, tile 8x32, lane = (row hh, 4-px strip sc).
// r9 skeleton + (a) true depth-2 pipeline (stage s+2 loads issued before
// COMPUTE(s): ~40KB in flight per CU at all times) and (b) f1 stride 40
// (2-way banks, was 8-way at 36). Raw s_barrier + lgkmcnt(0) only; the
// LDS-write of each stage waits only its own loads via counted vmcnt.
__global__ __launch_bounds__(NTHREADS, 3) void cv_kernel(
    const float* __restrict__ f1g, const float* __restrict__ f2g,
    float* __restrict__ outg) {
    __shared__ __align__(16) unsigned int lds[2][BUFN];

    const int tid = threadIdx.x;
    const int w0 = blockIdx.x * TW;
    const int h0 = blockIdx.y * TH;
    const int b  = blockIdx.z;

    // ---- slot A: f2 primary, 4 pairs x 16 rows x units 0..7 = 512 slots ----
    const bool roleA = (tid < 512);
    int offA = 0, ldA = 0;
    float mA = 0.f;
    if (roleA) {
        int pp = tid >> 7, r = (tid >> 3) & 15, u = tid & 7;
        int gh = h0 - 4 + r, gw = w0 - 4 + 4 * u;
        bool valid = (gh >= 0) && (gh < H_) && (gw >= 0) && (gw <= W_ - 4);
        int ghc = min(max(gh, 0), H_ - 1);
        int gwc = min(max(gw, 0), W_ - 4);
        offA = ((b * C_ + 2 * pp) * H_ + ghc) * W_ + gwc;
        ldA  = pp * F2PT + r * F2RS + 4 * u;
        mA   = valid ? 1.f : 0.f;
    }
    // ---- slot C: tid<128 -> f2 units 8,9; tid 128..383 -> f1 ----
    const bool roleC = (tid < 384);
    int offC = 0, ldC = 0;
    float mC = 0.f;
    const float* pC = f1g;
    if (tid < 128) {               // f2 u89: pp = tid>>5, r = (tid>>1)&15, u = 8+(tid&1)
        int pp = tid >> 5, r = (tid >> 1) & 15, u = 8 + (tid & 1);
        int gh = h0 - 4 + r, gw = w0 - 4 + 4 * u;
        bool valid = (gh >= 0) && (gh < H_) && (gw >= 0) && (gw <= W_ - 4);
        int ghc = min(max(gh, 0), H_ - 1);
        int gwc = min(max(gw, 0), W_ - 4);
        offC = ((b * C_ + 2 * pp) * H_ + ghc) * W_ + gwc;
        pC   = f2g;
        ldC  = pp * F2PT + r * F2RS + 4 * u;
        mC   = valid ? 1.f : 0.f;
    } else if (tid < 384) {        // f1: pp = t>>6, r = (t>>3)&7, u = t&7
        int t = tid - 128;
        int pp = t >> 6, r = (t >> 3) & 7, u = t & 7;
        offC = ((b * C_ + 2 * pp) * H_ + h0 + r) * W_ + w0 + 4 * u;
        pC   = f1g;
        ldC  = F1OFF + pp * F1PT + r * F1RS + 4 * u;
        mC   = 1.f;
    }

#define LOADST(Sa, Sb, Sc, Sd)                                                \
    do {                                                                      \
        if (roleA) {                                                          \
            Sa = *(const float4*)(f2g + offA);                                \
            Sb = *(const float4*)(f2g + offA + HW_);                          \
            offA += 8 * HW_;                                                  \
        }                                                                     \
        if (roleC) {                                                          \
            Sc = *(const float4*)(pC + offC);                                 \
            Sd = *(const float4*)(pC + offC + HW_);                           \
            offC += 8 * HW_;                                                  \
        }                                                                     \
    } while (0)

#define STOREST(bi, Sa, Sb, Sc, Sd)                                           \
    do {                                                                      \
        if (roleA) {                                                          \
            uint4 wv;                                                         \
            wv.x = pk(Sa.x * mA, Sb.x * mA);                                  \
            wv.y = pk(Sa.y * mA, Sb.y * mA);                                  \
            wv.z = pk(Sa.z * mA, Sb.z * mA);                                  \
            wv.w = pk(Sa.w * mA, Sb.w * mA);                                  \
            *(uint4*)(&lds[bi][ldA]) = wv;                                    \
        }                                                                     \
        if (roleC) {                                                          \
            uint4 w2;                                                         \
            w2.x = pk(Sc.x * mC, Sd.x * mC);                                  \
            w2.y = pk(Sc.y * mC, Sd.y * mC);                                  \
            w2.z = pk(Sc.z * mC, Sd.z * mC);                                  \
            w2.w = pk(Sc.w * mC, Sd.w * mC);                                  \
            *(uint4*)(&lds[bi][ldC]) = w2;                                    \
        }                                                                     \
    } while (0)

#define BAR()                                                                 \
    do {                                                                      \
        asm volatile("s_waitcnt lgkmcnt(0)" ::: "memory");                    \
        __builtin_amdgcn_s_barrier();                                         \
    } while (0)

    // ---- compute mapping ----
    const int di   = tid >> 6;       // 0..8
    const int lane = tid & 63;
    const int hh   = lane >> 3;      // 0..7
    const int sc   = lane & 7;       // 0..7, 4-px strip
    const int rd0  = (hh + di) * F2RS + 4 * sc;          // f2 units sc..sc+2
    const int rf0  = F1OFF + hh * F1RS + 4 * sc;         // f1 unit sc

    float acc[9][4];
#pragma unroll
    for (int j = 0; j < 9; ++j)
#pragma unroll
        for (int p = 0; p < 4; ++p) acc[j][p] = 0.f;

#define COMPUTE(bi)                                                           \
    do {                                                                      \
        _Pragma("unroll 2")                                                   \
        for (int q = 0; q < NPAIR; ++q) {                                     \
            const unsigned int* bf2 = &lds[bi][q * F2PT];                     \
            const unsigned int* bf1 = &lds[bi][q * F1PT];                     \
            uint4 fa = *(const uint4*)(bf2 + rd0);                            \
            uint4 fb = *(const uint4*)(bf2 + rd0 + 4);                        \
            uint4 fc = *(const uint4*)(bf2 + rd0 + 8);                        \
            uint4 ga = *(const uint4*)(bf1 + rf0);                            \
            unsigned int f2u[12] = {fa.x, fa.y, fa.z, fa.w, fb.x, fb.y,       \
                                    fb.z, fb.w, fc.x, fc.y, fc.z, fc.w};      \
            unsigned int f1u[4]  = {ga.x, ga.y, ga.z, ga.w};                  \
            _Pragma("unroll")                                                 \
            for (int j = 0; j < 9; ++j)                                       \
                _Pragma("unroll")                                             \
                for (int p = 0; p < 4; ++p)                                   \
                    acc[j][p] = dot2f16(f1u[p], f2u[p + j], acc[j][p]);       \
        }                                                                     \
    } while (0)

    float4 aA, bA, cA, dA, aB, bB, cB, dB;

    // prologue: stages 0,1 in flight; stage 0 -> buf0
    LOADST(aA, bA, cA, dA);            // stage 0
    LOADST(aB, bB, cB, dB);            // stage 1
    STOREST(0, aA, bA, cA, dA);        // waits stage-0 loads only (counted)
    BAR();

    // 16 stages of 8 channels, depth-2
    for (int s = 0; s < 14; s += 2) {
        LOADST(aA, bA, cA, dA);        // stage s+2 (in flight through compute)
        COMPUTE(0);                    // stage s
        STOREST(1, aB, bB, cB, dB);    // stage s+1 (counted vmcnt)
        BAR();
        LOADST(aB, bB, cB, dB);        // stage s+3
        COMPUTE(1);                    // stage s+1
        STOREST(0, aA, bA, cA, dA);    // stage s+2
        BAR();
    }
    COMPUTE(0);                        // stage 14
    STOREST(1, aB, bB, cB, dB);        // stage 15
    BAR();
    COMPUTE(1);                        // stage 15

    // ---- epilogue: mean over C and store ----
    const float inv = 1.0f / 128.0f;
    int obase = ((b * 81 + di * 9) * H_ + h0 + hh) * W_ + w0 + 4 * sc;
#pragma unroll
    for (int j = 0; j < 9; ++j) {
        float4 o = make_float4(acc[j][0] * inv, acc[j][1] * inv,
                               acc[j][2] * inv, acc[j][3] * inv);
        *(float4*)(outg + obase) = o;
        obase += HW_;
    }
}

extern "C" void kernel_launch(void* const* d_in, const int* in_sizes, int n_in,
                              void* d_out, int out_size, void* d_ws, size_t ws_size,
                              hipStream_t stream) {
    const float* f1 = (const float*)d_in[0];
    const float* f2 = (const float*)d_in[1];
    float* out = (float*)d_out;
    dim3 grid(W_ / TW, H_ / TH, B_);   // 8 x 16 x 8 = 1024 blocks
    cv_kernel<<<grid, NTHREADS, 0, stream>>>(f1, f2, out);
}